// Round 3
// baseline (165.618 us; speedup 1.0000x reference)
//
#include <hip/hip_runtime.h>
#include <math.h>

#define N_TOK 2048
#define DM    1024
#define HD    2048
#define NE    8
#define RMAX  5120                /* 4096 + 8*128 pad */
#define TMAX  40                  /* max 128-row tiles */

typedef short short8 __attribute__((ext_vector_type(8)));
typedef unsigned short u16x8 __attribute__((ext_vector_type(8)));
typedef float f32x4  __attribute__((ext_vector_type(4)));

__device__ inline unsigned short f2b(float f) {   // fp32 -> bf16 RNE
  unsigned int u = __float_as_uint(f);
  return (unsigned short)((u + 0x7FFFu + ((u >> 16) & 1u)) >> 16);
}
__device__ inline float b2f(unsigned short s) {
  return __uint_as_float(((unsigned int)s) << 16);
}
__device__ inline void gload_lds16(const void* g, void* l) {
  __builtin_amdgcn_global_load_lds(
      (const __attribute__((address_space(1))) unsigned int*)g,
      (__attribute__((address_space(3))) unsigned int*)l, 16, 0, 0);
}

// ---------------------------------------------------------------- gate
__global__ void gate_kernel(const float* __restrict__ inp,
                            const float* __restrict__ Wg,
                            const float* __restrict__ bg,
                            int* __restrict__ top_idx,
                            float* __restrict__ gate_w) {
  int wave = threadIdx.x >> 6;
  int lane = threadIdx.x & 63;
  int n = blockIdx.x * 4 + wave;
  if (n >= N_TOK) return;
  float acc[NE];
#pragma unroll
  for (int e = 0; e < NE; ++e) acc[e] = 0.f;
  const float4* wg4 = reinterpret_cast<const float4*>(Wg);
#pragma unroll
  for (int i = 0; i < DM / 64; ++i) {
    int d = i * 64 + lane;
    float x = inp[n * DM + d];
    float4 w0 = wg4[d * 2 + 0];
    float4 w1 = wg4[d * 2 + 1];
    acc[0] += x * w0.x; acc[1] += x * w0.y; acc[2] += x * w0.z; acc[3] += x * w0.w;
    acc[4] += x * w1.x; acc[5] += x * w1.y; acc[6] += x * w1.z; acc[7] += x * w1.w;
  }
#pragma unroll
  for (int off = 32; off > 0; off >>= 1) {
#pragma unroll
    for (int e = 0; e < NE; ++e) acc[e] += __shfl_xor(acc[e], off);
  }
  if (lane == 0) {
    float v0 = -1e30f, v1 = -1e30f; int i0 = -1, i1 = -1;
#pragma unroll
    for (int e = 0; e < NE; ++e) {
      float v = acc[e] + bg[e];
      if (v > v0)      { v1 = v0; i1 = i0; v0 = v; i0 = e; }
      else if (v > v1) { v1 = v;  i1 = e; }
    }
    float e1 = expf(v1 - v0);
    float s  = 1.f + e1;
    top_idx[n * 2]     = i0;
    top_idx[n * 2 + 1] = i1;
    gate_w[n * 2]      = 1.f / s;
    gate_w[n * 2 + 1]  = e1 / s;
  }
}

// ---------------------------------------------------------------- group
__global__ void group_kernel(const int* __restrict__ top_idx,
                             int* __restrict__ token_of,
                             int* __restrict__ inv_g,
                             int* __restrict__ tile_expert,
                             int* __restrict__ tile_row0,
                             int* __restrict__ n_tiles) {
  __shared__ int s_wtot[4];
  int tid = threadIdx.x, lane = tid & 63, wid = tid >> 6;
  int base = 0, tiles = 0;
  for (int e = 0; e < NE; ++e) {
    int cnt = 0;
    for (int c0 = 0; c0 < N_TOK; c0 += 256) {
      int n = c0 + tid;
      int t0 = top_idx[n * 2], t1 = top_idx[n * 2 + 1];
      bool f = (t0 == e) || (t1 == e);
      int k = (t0 == e) ? 0 : 1;
      unsigned long long m = __ballot(f);
      int lp = __popcll(m & ((1ull << lane) - 1ull));
      if (lane == 0) s_wtot[wid] = __popcll(m);
      __syncthreads();
      int wbase = 0;
      for (int w = 0; w < 4; ++w) if (w < wid) wbase += s_wtot[w];
      if (f) {
        int pos = base + cnt + wbase + lp;
        token_of[pos] = n;
        inv_g[n * 2 + k] = pos;
      }
      cnt += s_wtot[0] + s_wtot[1] + s_wtot[2] + s_wtot[3];
      __syncthreads();
    }
    int padded = (cnt + 127) & ~127;
    for (int i = cnt + tid; i < padded; i += 256) token_of[base + i] = -1;
    if (tid == 0) {
      for (int t = 0; t < padded / 128; ++t) {
        tile_expert[tiles + t] = e;
        tile_row0[tiles + t]   = base + t * 128;
      }
    }
    tiles += padded / 128;
    base  += padded;
    __syncthreads();
  }
  if (tid == 0) n_tiles[0] = tiles;
}

// ---------------------------------------------------------------- xcvt
__global__ void xcvt_kernel(const float* __restrict__ inp,
                            unsigned short* __restrict__ Xb) {
  int i = (blockIdx.x * 256 + threadIdx.x) * 8;
  float4 a = *(const float4*)(inp + i);
  float4 b = *(const float4*)(inp + i + 4);
  ushort4 pa, pb;
  pa.x = f2b(a.x); pa.y = f2b(a.y); pa.z = f2b(a.z); pa.w = f2b(a.w);
  pb.x = f2b(b.x); pb.y = f2b(b.y); pb.z = f2b(b.z); pb.w = f2b(b.w);
  *(ushort4*)(Xb + i)     = pa;
  *(ushort4*)(Xb + i + 4) = pb;
}

// ---------------------------------------------------------------- wcvt
// fp32 [K][N] -> bf16 k-chunked: chunk (kb=k/8, n) = 8 consecutive k for
// col n, stored at ((kb*N)+n)*8. Both load and store fully coalesced 16B.
__global__ __launch_bounds__(256) void wcvt_kernel(
    const float* __restrict__ W1, const float* __restrict__ W2,
    unsigned short* __restrict__ W1C, unsigned short* __restrict__ W2C) {
  int z = blockIdx.z;
  const float* src; unsigned short* dst; int K, N;
  if (z < NE) { src = W1 + (size_t)z * DM * HD; dst = W1C + (size_t)z * DM * HD; K = DM; N = HD; }
  else        { src = W2 + (size_t)(z - NE) * HD * DM; dst = W2C + (size_t)(z - NE) * HD * DM; K = HD; N = DM; }
  int n0 = blockIdx.x * 64, k0 = blockIdx.y * 64;
  if (n0 >= N || k0 >= K) return;
  __shared__ float s[64][68];
  int t = threadIdx.x;
  int q = t & 15, r0 = t >> 4;
#pragma unroll
  for (int p = 0; p < 4; ++p) {
    int row = p * 16 + r0;
    float4 v = *(const float4*)(src + (size_t)(k0 + row) * N + n0 + q * 4);
    *(float4*)&s[row][q * 4] = v;
  }
  __syncthreads();
  int n = t & 63;
  int kb0 = t >> 6;
#pragma unroll
  for (int p = 0; p < 2; ++p) {
    int kb = kb0 + p * 4;          // 0..7 within tile
    u16x8 o;
#pragma unroll
    for (int i = 0; i < 8; ++i) o[i] = f2b(s[kb * 8 + i][n]);
    *(u16x8*)(dst + ((size_t)(k0 / 8 + kb) * N + n0 + n) * 8) = o;
  }
}

// ---------------------------------------------------------------- ffn1
// H[row][h] = gelu( X[tok(row)] . W1[h col] + b1 ), 128x128 tile, MFMA bf16
__global__ __launch_bounds__(256) void ffn1_mfma(
    const unsigned short* __restrict__ Xb,
    const unsigned short* __restrict__ W1C,
    const float* __restrict__ b1,
    const unsigned short* __restrict__ zbuf,
    const int* __restrict__ token_of, const int* __restrict__ tile_expert,
    const int* __restrict__ tile_row0, const int* __restrict__ n_tiles,
    unsigned short* __restrict__ Hbuf) {
  if ((int)blockIdx.x >= n_tiles[0]) return;
  int e    = tile_expert[blockIdx.x];
  int row0 = tile_row0[blockIdx.x];
  int h0   = blockIdx.y * 128;
  __shared__ __align__(16) unsigned short Asl[128][32];
  __shared__ __align__(16) unsigned short Bsl[128][32];
  int tid = threadIdx.x, lane = tid & 63;
  int wid = tid >> 6, wr = wid >> 1, wc = wid & 1;
  int l15 = lane & 15, l4 = lane >> 4;

  int tk[2];
#pragma unroll
  for (int q = 0; q < 2; ++q) tk[q] = token_of[row0 + ((tid + q * 256) >> 2)];

  f32x4 acc[4][4] = {};
  const unsigned short* W1e = W1C + (size_t)e * DM * HD;   // k-chunked

  for (int kc = 0; kc < DM; kc += 32) {
    __syncthreads();
#pragma unroll
    for (int q = 0; q < 2; ++q) {
      int idx = tid + q * 256;
      const unsigned short* ga = (tk[q] < 0)
          ? zbuf
          : Xb + (size_t)tk[q] * DM + kc + (idx & 3) * 8;
      gload_lds16(ga, (char*)&Asl[0][0] + (size_t)idx * 16);
      const unsigned short* gb =
          W1e + ((size_t)((kc >> 3) + (idx & 3)) * HD + h0 + (idx >> 2)) * 8;
      gload_lds16(gb, (char*)&Bsl[0][0] + (size_t)idx * 16);
    }
    __syncthreads();
    short8 a[4], b[4];
#pragma unroll
    for (int m = 0; m < 4; ++m)
      a[m] = *(const short8*)&Asl[wr * 64 + m * 16 + l15][l4 * 8];
#pragma unroll
    for (int n = 0; n < 4; ++n)
      b[n] = *(const short8*)&Bsl[wc * 64 + n * 16 + l15][l4 * 8];
#pragma unroll
    for (int m = 0; m < 4; ++m)
#pragma unroll
      for (int n = 0; n < 4; ++n)
        acc[m][n] = __builtin_amdgcn_mfma_f32_16x16x32_bf16(a[m], b[n], acc[m][n], 0, 0, 0);
  }

  float bias[4];
#pragma unroll
  for (int n = 0; n < 4; ++n) bias[n] = b1[e * HD + h0 + wc * 64 + n * 16 + l15];
#pragma unroll
  for (int m = 0; m < 4; ++m) {
#pragma unroll
    for (int n = 0; n < 4; ++n) {
      int col = h0 + wc * 64 + n * 16 + l15;
#pragma unroll
      for (int j = 0; j < 4; ++j) {
        int row = row0 + wr * 64 + m * 16 + l4 * 4 + j;
        float x = acc[m][n][j] + bias[n];
        float g = 0.5f * x * (1.f + tanhf(0.7978845608f * (x + 0.044715f * x * x * x)));
        Hbuf[(size_t)row * HD + col] = f2b(g);
      }
    }
  }
}

// ---------------------------------------------------------------- ffn2
__global__ __launch_bounds__(256) void ffn2_mfma(
    const unsigned short* __restrict__ Hbuf,
    const unsigned short* __restrict__ W2C,
    const float* __restrict__ b2,
    const int* __restrict__ tile_expert, const int* __restrict__ tile_row0,
    const int* __restrict__ n_tiles,
    unsigned short* __restrict__ Ybuf) {
  if ((int)blockIdx.x >= n_tiles[0]) return;
  int e    = tile_expert[blockIdx.x];
  int row0 = tile_row0[blockIdx.x];
  int d0   = blockIdx.y * 128;
  __shared__ __align__(16) unsigned short Asl[128][32];
  __shared__ __align__(16) unsigned short Bsl[128][32];
  int tid = threadIdx.x, lane = tid & 63;
  int wid = tid >> 6, wr = wid >> 1, wc = wid & 1;
  int l15 = lane & 15, l4 = lane >> 4;

  f32x4 acc[4][4] = {};
  const unsigned short* W2e = W2C + (size_t)e * DM * HD;   // k-chunked

  for (int kc = 0; kc < HD; kc += 32) {
    __syncthreads();
#pragma unroll
    for (int q = 0; q < 2; ++q) {
      int idx = tid + q * 256;
      const unsigned short* ga =
          Hbuf + (size_t)(row0 + (idx >> 2)) * HD + kc + (idx & 3) * 8;
      gload_lds16(ga, (char*)&Asl[0][0] + (size_t)idx * 16);
      const unsigned short* gb =
          W2e + ((size_t)((kc >> 3) + (idx & 3)) * DM + d0 + (idx >> 2)) * 8;
      gload_lds16(gb, (char*)&Bsl[0][0] + (size_t)idx * 16);
    }
    __syncthreads();
    short8 a[4], b[4];
#pragma unroll
    for (int m = 0; m < 4; ++m)
      a[m] = *(const short8*)&Asl[wr * 64 + m * 16 + l15][l4 * 8];
#pragma unroll
    for (int n = 0; n < 4; ++n)
      b[n] = *(const short8*)&Bsl[wc * 64 + n * 16 + l15][l4 * 8];
#pragma unroll
    for (int m = 0; m < 4; ++m)
#pragma unroll
      for (int n = 0; n < 4; ++n)
        acc[m][n] = __builtin_amdgcn_mfma_f32_16x16x32_bf16(a[m], b[n], acc[m][n], 0, 0, 0);
  }

  float bias[4];
#pragma unroll
  for (int n = 0; n < 4; ++n) bias[n] = b2[e * DM + d0 + wc * 64 + n * 16 + l15];
#pragma unroll
  for (int m = 0; m < 4; ++m) {
#pragma unroll
    for (int n = 0; n < 4; ++n) {
      int col = d0 + wc * 64 + n * 16 + l15;
#pragma unroll
      for (int j = 0; j < 4; ++j) {
        int row = row0 + wr * 64 + m * 16 + l4 * 4 + j;
        Ybuf[(size_t)row * DM + col] = f2b(acc[m][n][j] + bias[n]);
      }
    }
  }
}

// ---------------------------------------------------------------- combine
__global__ void combine_kernel(const unsigned short* __restrict__ Ybuf,
                               const int* __restrict__ inv_g,
                               const float* __restrict__ gate_w,
                               float* __restrict__ out) {
  int n = blockIdx.x;
  int r0 = inv_g[n * 2], r1 = inv_g[n * 2 + 1];
  float g0 = gate_w[n * 2], g1 = gate_w[n * 2 + 1];
  int i = threadIdx.x;
  ushort4 a = *(const ushort4*)(Ybuf + (size_t)r0 * DM + i * 4);
  ushort4 b = *(const ushort4*)(Ybuf + (size_t)r1 * DM + i * 4);
  float4 rv;
  rv.x = g0 * b2f(a.x) + g1 * b2f(b.x);
  rv.y = g0 * b2f(a.y) + g1 * b2f(b.y);
  rv.z = g0 * b2f(a.z) + g1 * b2f(b.z);
  rv.w = g0 * b2f(a.w) + g1 * b2f(b.w);
  *(float4*)(out + (size_t)n * DM + i * 4) = rv;
}

// ---------------------------------------------------------------- launch
extern "C" void kernel_launch(void* const* d_in, const int* in_sizes, int n_in,
                              void* d_out, int out_size, void* d_ws, size_t ws_size,
                              hipStream_t stream) {
  const float* inp = (const float*)d_in[0];
  const float* Wg  = (const float*)d_in[1];
  const float* bg  = (const float*)d_in[2];
  const float* W1  = (const float*)d_in[3];
  const float* b1  = (const float*)d_in[4];
  const float* W2  = (const float*)d_in[5];
  const float* b2  = (const float*)d_in[6];
  float* out = (float*)d_out;

  char* ws = (char*)d_ws;
  size_t off = 0;
  auto alloc = [&](size_t bytes) {
    size_t o = off;
    off = (off + bytes + 255) & ~(size_t)255;
    return o;
  };
  int*   top_idx     = (int*)  (ws + alloc(N_TOK * 2 * sizeof(int)));
  float* gate_w      = (float*)(ws + alloc(N_TOK * 2 * sizeof(float)));
  int*   token_of    = (int*)  (ws + alloc(RMAX * sizeof(int)));
  int*   inv_g       = (int*)  (ws + alloc(N_TOK * 2 * sizeof(int)));
  int*   tile_expert = (int*)  (ws + alloc(TMAX * sizeof(int)));
  int*   tile_row0   = (int*)  (ws + alloc(TMAX * sizeof(int)));
  int*   n_tiles     = (int*)  (ws + alloc(sizeof(int)));
  unsigned short* zbuf = (unsigned short*)(ws + alloc(256));
  unsigned short* Xb   = (unsigned short*)(ws + alloc((size_t)N_TOK * DM * 2));
  unsigned short* W1C  = (unsigned short*)(ws + alloc((size_t)NE * DM * HD * 2));
  unsigned short* W2C  = (unsigned short*)(ws + alloc((size_t)NE * DM * HD * 2));
  unsigned short* Hbuf = (unsigned short*)(ws + alloc((size_t)RMAX * HD * 2));
  unsigned short* Ybuf = (unsigned short*)(ws + alloc((size_t)RMAX * DM * 2));
  (void)ws_size;

  hipMemsetAsync(zbuf, 0, 256, stream);
  gate_kernel<<<N_TOK / 4, 256, 0, stream>>>(inp, Wg, bg, top_idx, gate_w);
  group_kernel<<<1, 256, 0, stream>>>(top_idx, token_of, inv_g,
                                      tile_expert, tile_row0, n_tiles);
  xcvt_kernel<<<(N_TOK * DM) / (256 * 8), 256, 0, stream>>>(inp, Xb);
  wcvt_kernel<<<dim3(32, 32, 2 * NE), 256, 0, stream>>>(W1, W2, W1C, W2C);
  ffn1_mfma<<<dim3(TMAX, HD / 128), 256, 0, stream>>>(
      Xb, W1C, b1, zbuf, token_of, tile_expert, tile_row0, n_tiles, Hbuf);
  ffn2_mfma<<<dim3(TMAX, DM / 128), 256, 0, stream>>>(
      Hbuf, W2C, b2, tile_expert, tile_row0, n_tiles, Ybuf);
  combine_kernel<<<N_TOK, 256, 0, stream>>>(Ybuf, inv_g, gate_w, out);
}

// Round 4
// 165.464 us; speedup vs baseline: 1.0009x; 1.0009x over previous
//
#include <hip/hip_runtime.h>
#include <math.h>

#define N_TOK 2048
#define DM    1024
#define HD    2048
#define NE    8
#define RMAX  5120                /* 4096 + 8*128 pad */
#define TMAX  40                  /* max 128-row tiles */

typedef short short8 __attribute__((ext_vector_type(8)));
typedef unsigned short u16x8 __attribute__((ext_vector_type(8)));
typedef float f32x4  __attribute__((ext_vector_type(4)));

__device__ inline unsigned short f2b(float f) {   // fp32 -> bf16 RNE
  unsigned int u = __float_as_uint(f);
  return (unsigned short)((u + 0x7FFFu + ((u >> 16) & 1u)) >> 16);
}
__device__ inline float b2f(unsigned short s) {
  return __uint_as_float(((unsigned int)s) << 16);
}
__device__ inline void gload_lds16(const void* g, void* l) {
  __builtin_amdgcn_global_load_lds(
      (const __attribute__((address_space(1))) unsigned int*)g,
      (__attribute__((address_space(3))) unsigned int*)l, 16, 0, 0);
}

// ---------------------------------------------------------------- gate
__global__ void gate_kernel(const float* __restrict__ inp,
                            const float* __restrict__ Wg,
                            const float* __restrict__ bg,
                            int* __restrict__ top_idx,
                            float* __restrict__ gate_w) {
  int wave = threadIdx.x >> 6;
  int lane = threadIdx.x & 63;
  int n = blockIdx.x * 4 + wave;
  if (n >= N_TOK) return;
  float acc[NE];
#pragma unroll
  for (int e = 0; e < NE; ++e) acc[e] = 0.f;
  const float4* wg4 = reinterpret_cast<const float4*>(Wg);
#pragma unroll
  for (int i = 0; i < DM / 64; ++i) {
    int d = i * 64 + lane;
    float x = inp[n * DM + d];
    float4 w0 = wg4[d * 2 + 0];
    float4 w1 = wg4[d * 2 + 1];
    acc[0] += x * w0.x; acc[1] += x * w0.y; acc[2] += x * w0.z; acc[3] += x * w0.w;
    acc[4] += x * w1.x; acc[5] += x * w1.y; acc[6] += x * w1.z; acc[7] += x * w1.w;
  }
#pragma unroll
  for (int off = 32; off > 0; off >>= 1) {
#pragma unroll
    for (int e = 0; e < NE; ++e) acc[e] += __shfl_xor(acc[e], off);
  }
  if (lane == 0) {
    float v0 = -1e30f, v1 = -1e30f; int i0 = -1, i1 = -1;
#pragma unroll
    for (int e = 0; e < NE; ++e) {
      float v = acc[e] + bg[e];
      if (v > v0)      { v1 = v0; i1 = i0; v0 = v; i0 = e; }
      else if (v > v1) { v1 = v;  i1 = e; }
    }
    float e1 = expf(v1 - v0);
    float s  = 1.f + e1;
    top_idx[n * 2]     = i0;
    top_idx[n * 2 + 1] = i1;
    gate_w[n * 2]      = 1.f / s;
    gate_w[n * 2 + 1]  = e1 / s;
  }
}

// ---------------------------------------------------------------- group
__global__ void group_kernel(const int* __restrict__ top_idx,
                             int* __restrict__ token_of,
                             int* __restrict__ inv_g,
                             int* __restrict__ tile_expert,
                             int* __restrict__ tile_row0,
                             int* __restrict__ n_tiles) {
  __shared__ int s_wtot[4];
  int tid = threadIdx.x, lane = tid & 63, wid = tid >> 6;
  int base = 0, tiles = 0;
  for (int e = 0; e < NE; ++e) {
    int cnt = 0;
    for (int c0 = 0; c0 < N_TOK; c0 += 256) {
      int n = c0 + tid;
      int t0 = top_idx[n * 2], t1 = top_idx[n * 2 + 1];
      bool f = (t0 == e) || (t1 == e);
      int k = (t0 == e) ? 0 : 1;
      unsigned long long m = __ballot(f);
      int lp = __popcll(m & ((1ull << lane) - 1ull));
      if (lane == 0) s_wtot[wid] = __popcll(m);
      __syncthreads();
      int wbase = 0;
      for (int w = 0; w < 4; ++w) if (w < wid) wbase += s_wtot[w];
      if (f) {
        int pos = base + cnt + wbase + lp;
        token_of[pos] = n;
        inv_g[n * 2 + k] = pos;
      }
      cnt += s_wtot[0] + s_wtot[1] + s_wtot[2] + s_wtot[3];
      __syncthreads();
    }
    int padded = (cnt + 127) & ~127;
    for (int i = cnt + tid; i < padded; i += 256) token_of[base + i] = -1;
    if (tid == 0) {
      for (int t = 0; t < padded / 128; ++t) {
        tile_expert[tiles + t] = e;
        tile_row0[tiles + t]   = base + t * 128;
      }
    }
    tiles += padded / 128;
    base  += padded;
    __syncthreads();
  }
  if (tid == 0) n_tiles[0] = tiles;
}

// ---------------------------------------------------------------- xcvt
__global__ void xcvt_kernel(const float* __restrict__ inp,
                            unsigned short* __restrict__ Xb) {
  int i = (blockIdx.x * 256 + threadIdx.x) * 8;
  float4 a = *(const float4*)(inp + i);
  float4 b = *(const float4*)(inp + i + 4);
  ushort4 pa, pb;
  pa.x = f2b(a.x); pa.y = f2b(a.y); pa.z = f2b(a.z); pa.w = f2b(a.w);
  pb.x = f2b(b.x); pb.y = f2b(b.y); pb.z = f2b(b.z); pb.w = f2b(b.w);
  *(ushort4*)(Xb + i)     = pa;
  *(ushort4*)(Xb + i + 4) = pb;
}

// ---------------------------------------------------------------- wcvt
// LDS-free transpose-convert. fp32 [K][N] -> bf16 k-chunked:
// chunk (kb, n) = 8 consecutive k of col n at ((kb*N)+n)*8.
// Lane owns one column, 8 k-rows: 8 loads (256B/wave coalesced), 1 store.
__global__ __launch_bounds__(256) void wcvt_kernel(
    const float* __restrict__ W1, const float* __restrict__ W2,
    unsigned short* __restrict__ W1C, unsigned short* __restrict__ W2C) {
  int z = blockIdx.z;
  const float* src; unsigned short* dst; int K, N;
  if (z < NE) { src = W1 + (size_t)z * DM * HD; dst = W1C + (size_t)z * DM * HD; K = DM; N = HD; }
  else        { src = W2 + (size_t)(z - NE) * HD * DM; dst = W2C + (size_t)(z - NE) * HD * DM; K = HD; N = DM; }
  int n0 = blockIdx.x * 64, k0 = blockIdx.y * 32;
  if (n0 >= N || k0 >= K) return;
  int t = threadIdx.x;
  int n = t & 63, kg = t >> 6;            // 4 k-groups of 8
  const float* s = src + (size_t)(k0 + kg * 8) * N + n0 + n;
  float v[8];
#pragma unroll
  for (int i = 0; i < 8; ++i) v[i] = s[(size_t)i * N];
  u16x8 o;
#pragma unroll
  for (int i = 0; i < 8; ++i) o[i] = f2b(v[i]);
  *(u16x8*)(dst + ((size_t)(k0 / 8 + kg) * N + n0 + n) * 8) = o;
}

// ---------------------------------------------------------------- ffn1
// 128x64 tile, 2x2 waves, swizzled chunk slots (conflict-free ds_read_b128)
__global__ __launch_bounds__(256) void ffn1_mfma(
    const unsigned short* __restrict__ Xb,
    const unsigned short* __restrict__ W1C,
    const float* __restrict__ b1,
    const unsigned short* __restrict__ zbuf,
    const int* __restrict__ token_of, const int* __restrict__ tile_expert,
    const int* __restrict__ tile_row0, const int* __restrict__ n_tiles,
    unsigned short* __restrict__ Hbuf) {
  if ((int)blockIdx.x >= n_tiles[0]) return;
  int e    = tile_expert[blockIdx.x];
  int row0 = tile_row0[blockIdx.x];
  int h0   = blockIdx.y * 64;
  __shared__ __align__(16) unsigned short Asl[128][32];
  __shared__ __align__(16) unsigned short Bsl[64][32];
  int tid = threadIdx.x, lane = tid & 63;
  int wid = tid >> 6, wr = wid >> 1, wc = wid & 1;
  int l15 = lane & 15, l4 = lane >> 4;
  int sw  = (l15 >> 1) & 3;              // read-side slot XOR

  // staging descriptors (slot-swizzled global chunk index)
  int ar[2], asg[2];
  int tk[2];
#pragma unroll
  for (int q = 0; q < 2; ++q) {
    int idx = tid + q * 256;
    ar[q]  = idx >> 2;
    asg[q] = (idx & 3) ^ ((ar[q] >> 1) & 3);
    tk[q]  = token_of[row0 + ar[q]];
  }
  int bc  = tid >> 2;
  int bsg = (tid & 3) ^ ((bc >> 1) & 3);

  f32x4 acc[4][2] = {};
  const unsigned short* W1e = W1C + (size_t)e * DM * HD;   // k-chunked

  for (int kc = 0; kc < DM; kc += 32) {
    __syncthreads();
#pragma unroll
    for (int q = 0; q < 2; ++q) {
      int idx = tid + q * 256;
      const unsigned short* ga = (tk[q] < 0)
          ? zbuf
          : Xb + (size_t)tk[q] * DM + kc + asg[q] * 8;
      gload_lds16(ga, (char*)&Asl[0][0] + (size_t)idx * 16);
    }
    {
      const unsigned short* gb =
          W1e + ((size_t)((kc >> 3) + bsg) * HD + h0 + bc) * 8;
      gload_lds16(gb, (char*)&Bsl[0][0] + (size_t)tid * 16);
    }
    __syncthreads();
    short8 a[4], b[2];
#pragma unroll
    for (int m = 0; m < 4; ++m) {
      int R = wr * 64 + m * 16 + l15;
      a[m] = *(const short8*)((const char*)&Asl[0][0] + R * 64 + ((l4 ^ sw) << 4));
    }
#pragma unroll
    for (int n = 0; n < 2; ++n) {
      int R = wc * 32 + n * 16 + l15;
      b[n] = *(const short8*)((const char*)&Bsl[0][0] + R * 64 + ((l4 ^ sw) << 4));
    }
#pragma unroll
    for (int m = 0; m < 4; ++m)
#pragma unroll
      for (int n = 0; n < 2; ++n)
        acc[m][n] = __builtin_amdgcn_mfma_f32_16x16x32_bf16(a[m], b[n], acc[m][n], 0, 0, 0);
  }

  float bias[2];
#pragma unroll
  for (int n = 0; n < 2; ++n) bias[n] = b1[e * HD + h0 + wc * 32 + n * 16 + l15];
#pragma unroll
  for (int m = 0; m < 4; ++m) {
#pragma unroll
    for (int n = 0; n < 2; ++n) {
      int col = h0 + wc * 32 + n * 16 + l15;
#pragma unroll
      for (int j = 0; j < 4; ++j) {
        int row = row0 + wr * 64 + m * 16 + l4 * 4 + j;
        float x = acc[m][n][j] + bias[n];
        float g = 0.5f * x * (1.f + tanhf(0.7978845608f * (x + 0.044715f * x * x * x)));
        Hbuf[(size_t)row * HD + col] = f2b(g);
      }
    }
  }
}

// ---------------------------------------------------------------- ffn2
__global__ __launch_bounds__(256) void ffn2_mfma(
    const unsigned short* __restrict__ Hbuf,
    const unsigned short* __restrict__ W2C,
    const float* __restrict__ b2,
    const int* __restrict__ tile_expert, const int* __restrict__ tile_row0,
    const int* __restrict__ n_tiles,
    unsigned short* __restrict__ Ybuf) {
  if ((int)blockIdx.x >= n_tiles[0]) return;
  int e    = tile_expert[blockIdx.x];
  int row0 = tile_row0[blockIdx.x];
  int d0   = blockIdx.y * 64;
  __shared__ __align__(16) unsigned short Asl[128][32];
  __shared__ __align__(16) unsigned short Bsl[64][32];
  int tid = threadIdx.x, lane = tid & 63;
  int wid = tid >> 6, wr = wid >> 1, wc = wid & 1;
  int l15 = lane & 15, l4 = lane >> 4;
  int sw  = (l15 >> 1) & 3;

  int ar[2], asg[2];
#pragma unroll
  for (int q = 0; q < 2; ++q) {
    int idx = tid + q * 256;
    ar[q]  = idx >> 2;
    asg[q] = (idx & 3) ^ ((ar[q] >> 1) & 3);
  }
  int bc  = tid >> 2;
  int bsg = (tid & 3) ^ ((bc >> 1) & 3);

  f32x4 acc[4][2] = {};
  const unsigned short* W2e = W2C + (size_t)e * DM * HD;   // k-chunked

  for (int kc = 0; kc < HD; kc += 32) {
    __syncthreads();
#pragma unroll
    for (int q = 0; q < 2; ++q) {
      int idx = tid + q * 256;
      const unsigned short* ga =
          Hbuf + (size_t)(row0 + ar[q]) * HD + kc + asg[q] * 8;
      gload_lds16(ga, (char*)&Asl[0][0] + (size_t)idx * 16);
    }
    {
      const unsigned short* gb =
          W2e + ((size_t)((kc >> 3) + bsg) * DM + d0 + bc) * 8;
      gload_lds16(gb, (char*)&Bsl[0][0] + (size_t)tid * 16);
    }
    __syncthreads();
    short8 a[4], b[2];
#pragma unroll
    for (int m = 0; m < 4; ++m) {
      int R = wr * 64 + m * 16 + l15;
      a[m] = *(const short8*)((const char*)&Asl[0][0] + R * 64 + ((l4 ^ sw) << 4));
    }
#pragma unroll
    for (int n = 0; n < 2; ++n) {
      int R = wc * 32 + n * 16 + l15;
      b[n] = *(const short8*)((const char*)&Bsl[0][0] + R * 64 + ((l4 ^ sw) << 4));
    }
#pragma unroll
    for (int m = 0; m < 4; ++m)
#pragma unroll
      for (int n = 0; n < 2; ++n)
        acc[m][n] = __builtin_amdgcn_mfma_f32_16x16x32_bf16(a[m], b[n], acc[m][n], 0, 0, 0);
  }

  float bias[2];
#pragma unroll
  for (int n = 0; n < 2; ++n) bias[n] = b2[e * DM + d0 + wc * 32 + n * 16 + l15];
#pragma unroll
  for (int m = 0; m < 4; ++m) {
#pragma unroll
    for (int n = 0; n < 2; ++n) {
      int col = d0 + wc * 32 + n * 16 + l15;
#pragma unroll
      for (int j = 0; j < 4; ++j) {
        int row = row0 + wr * 64 + m * 16 + l4 * 4 + j;
        Ybuf[(size_t)row * DM + col] = f2b(acc[m][n][j] + bias[n]);
      }
    }
  }
}

// ---------------------------------------------------------------- combine
__global__ void combine_kernel(const unsigned short* __restrict__ Ybuf,
                               const int* __restrict__ inv_g,
                               const float* __restrict__ gate_w,
                               float* __restrict__ out) {
  int n = blockIdx.x;
  int r0 = inv_g[n * 2], r1 = inv_g[n * 2 + 1];
  float g0 = gate_w[n * 2], g1 = gate_w[n * 2 + 1];
  int i = threadIdx.x;
  ushort4 a = *(const ushort4*)(Ybuf + (size_t)r0 * DM + i * 4);
  ushort4 b = *(const ushort4*)(Ybuf + (size_t)r1 * DM + i * 4);
  float4 rv;
  rv.x = g0 * b2f(a.x) + g1 * b2f(b.x);
  rv.y = g0 * b2f(a.y) + g1 * b2f(b.y);
  rv.z = g0 * b2f(a.z) + g1 * b2f(b.z);
  rv.w = g0 * b2f(a.w) + g1 * b2f(b.w);
  *(float4*)(out + (size_t)n * DM + i * 4) = rv;
}

// ---------------------------------------------------------------- launch
extern "C" void kernel_launch(void* const* d_in, const int* in_sizes, int n_in,
                              void* d_out, int out_size, void* d_ws, size_t ws_size,
                              hipStream_t stream) {
  const float* inp = (const float*)d_in[0];
  const float* Wg  = (const float*)d_in[1];
  const float* bg  = (const float*)d_in[2];
  const float* W1  = (const float*)d_in[3];
  const float* b1  = (const float*)d_in[4];
  const float* W2  = (const float*)d_in[5];
  const float* b2  = (const float*)d_in[6];
  float* out = (float*)d_out;

  char* ws = (char*)d_ws;
  size_t off = 0;
  auto alloc = [&](size_t bytes) {
    size_t o = off;
    off = (off + bytes + 255) & ~(size_t)255;
    return o;
  };
  int*   top_idx     = (int*)  (ws + alloc(N_TOK * 2 * sizeof(int)));
  float* gate_w      = (float*)(ws + alloc(N_TOK * 2 * sizeof(float)));
  int*   token_of    = (int*)  (ws + alloc(RMAX * sizeof(int)));
  int*   inv_g       = (int*)  (ws + alloc(N_TOK * 2 * sizeof(int)));
  int*   tile_expert = (int*)  (ws + alloc(TMAX * sizeof(int)));
  int*   tile_row0   = (int*)  (ws + alloc(TMAX * sizeof(int)));
  int*   n_tiles     = (int*)  (ws + alloc(sizeof(int)));
  unsigned short* zbuf = (unsigned short*)(ws + alloc(256));
  unsigned short* Xb   = (unsigned short*)(ws + alloc((size_t)N_TOK * DM * 2));
  unsigned short* W1C  = (unsigned short*)(ws + alloc((size_t)NE * DM * HD * 2));
  unsigned short* W2C  = (unsigned short*)(ws + alloc((size_t)NE * DM * HD * 2));
  unsigned short* Hbuf = (unsigned short*)(ws + alloc((size_t)RMAX * HD * 2));
  unsigned short* Ybuf = (unsigned short*)(ws + alloc((size_t)RMAX * DM * 2));
  (void)ws_size;

  hipMemsetAsync(zbuf, 0, 256, stream);
  gate_kernel<<<N_TOK / 4, 256, 0, stream>>>(inp, Wg, bg, top_idx, gate_w);
  group_kernel<<<1, 256, 0, stream>>>(top_idx, token_of, inv_g,
                                      tile_expert, tile_row0, n_tiles);
  xcvt_kernel<<<(N_TOK * DM) / (256 * 8), 256, 0, stream>>>(inp, Xb);
  wcvt_kernel<<<dim3(32, 64, 2 * NE), 256, 0, stream>>>(W1, W2, W1C, W2C);
  ffn1_mfma<<<dim3(TMAX, HD / 64), 256, 0, stream>>>(
      Xb, W1C, b1, zbuf, token_of, tile_expert, tile_row0, n_tiles, Hbuf);
  ffn2_mfma<<<dim3(TMAX, DM / 64), 256, 0, stream>>>(
      Hbuf, W2C, b2, tile_expert, tile_row0, n_tiles, Ybuf);
  combine_kernel<<<N_TOK, 256, 0, stream>>>(Ybuf, inv_g, gate_w, out);
}